// Round 5
// baseline (6492.645 us; speedup 1.0000x reference)
//
#include <hip/hip_runtime.h>

typedef short s16;
typedef short bf16x8 __attribute__((ext_vector_type(8)));
typedef float f32x4 __attribute__((ext_vector_type(4)));

constexpr int kB = 1024, kT = 64, kD = 512, kH = 256;
constexpr int NSEG = 14;
// element counts per input (setup_inputs order) and exclusive prefix offsets
// z_init t  W1     b1  W2    b2  W3     b3  Wqkv   bqkv Wo     bo  gamma beta
// 524288 64 131072 256 65536 256 131072 512 786432 1536 262144 512 512   512
constexpr int kOff[NSEG] = {0, 524288, 524352, 655424, 655680, 721216, 721472,
                            852544, 853056, 1639488, 1641024, 1903168, 1903680, 1904192};
constexpr int kTotalConv = 1904704;

__device__ __forceinline__ float bs2f(s16 s) {
    return __uint_as_float(((unsigned)(unsigned short)s) << 16);
}
__device__ __forceinline__ s16 f2bs(float f) {
    unsigned u = __float_as_uint(f);
    unsigned r = (u + 0x7fffu + ((u >> 16) & 1u)) >> 16;
    return (s16)r;
}
__device__ __forceinline__ f32x4 mfma16(bf16x8 a, bf16x8 b, f32x4 c) {
    return __builtin_amdgcn_mfma_f32_16x16x32_bf16(a, b, c, 0, 0, 0);
}
__device__ __forceinline__ float gelu(float x) {
    return 0.5f * x * (1.0f + erff(x * 0.70710678118654752f));
}

// ---------------------------------------------------------------------------
// dtype detect: t_steps[0..1] as one 32-bit word. bf16: [0, bf16(0.05)] ->
// 0x3D4D0000 != 0.  f32: first float 0.0f -> 0x00000000.
// flag = 1 means inputs are f32.
// ---------------------------------------------------------------------------
__global__ void detect_kernel(const unsigned* __restrict__ ts, int* __restrict__ flag) {
    if (threadIdx.x == 0 && blockIdx.x == 0) flag[0] = (ts[0] == 0u) ? 1 : 0;
}

struct ConvArgs { const void* src[NSEG]; };

__global__ __launch_bounds__(256) void convert_kernel(ConvArgs a, s16* __restrict__ dst,
                                                      const int* __restrict__ flag) {
    const int f = flag[0];
    for (int i = blockIdx.x * 256 + threadIdx.x; i < kTotalConv; i += gridDim.x * 256) {
        int s = 0;
        #pragma unroll
        for (int j = 1; j < NSEG; ++j) if (i >= kOff[j]) s = j;
        int local = i - kOff[s];
        s16 v;
        if (f) v = f2bs(((const float*)a.src[s])[local]);
        else   v = ((const s16*)a.src[s])[local];
        dst[i] = v;
    }
}

// ============================================================================
// ODE kernel: 64 blocks x 512 threads (8 waves). Block owns 16 rows of B.
// Wave w owns h-cols [w*32,w*32+32) for GEMM1/2 and out-cols [w*64,w*64+64)
// for GEMM3.  Latency fix: weight fragments are BATCH-LOADED into named
// register arrays ahead of the consuming MFMAs — W2 is loop-RESIDENT (loaded
// once, 64 VGPRs); W1 (32 frags) batch-issued at eval start; W3 in two
// 16-frag batches overlapped with GEMM2.  This collapses ~64 serialized
// ~400-cyc L2 latency events per eval into ~4 batched ones (note: barriers
// drain vmcnt(0), so pre-barrier issues complete AT the barrier — one shared
// wait, not per-load exposure).  All array indices compile-time (full unroll
// -> no scratch).  Peak live ~240 VGPR < 256 cap of (512,2).
// ============================================================================
__global__ __launch_bounds__(512, 2) void ode_kernel(
    const s16* __restrict__ zin, const s16* __restrict__ ts,
    const s16* __restrict__ W1, const s16* __restrict__ b1,
    const s16* __restrict__ W2, const s16* __restrict__ b2,
    const s16* __restrict__ W3, const s16* __restrict__ b3,
    s16* __restrict__ stage)
{
    __shared__ __align__(16) s16 sArg[16 * 520];   // [16][520]
    __shared__ __align__(16) s16 sH1[16 * 264];    // [16][264]
    __shared__ __align__(16) s16 sH2[16 * 264];    // [16][264]
    __shared__ float sScale[16];

    const int tid = threadIdx.x;
    const int w = tid >> 6;          // wave 0..7
    const int lane = tid & 63;
    const int quad = lane >> 4;
    const int c = lane & 15;
    const int r0 = blockIdx.x * 16;

    const float dt  = bs2f(ts[1]) - bs2f(ts[0]);
    const float hdt = 0.5f * dt;
    const float dt6 = dt / 6.0f;

    // ---- per-row adaptive scale (wave w handles rows w and w+8) ----
    for (int r = w; r < 16; r += 8) {
        const s16* zrow = zin + (size_t)(r0 + r) * kD;
        float sum = 0.f, ssq = 0.f;
        for (int i = 0; i < 8; ++i) {
            float v = bs2f(zrow[lane + 64 * i]);
            sum += v; ssq += v * v;
        }
        for (int m = 1; m < 64; m <<= 1) {
            sum += __shfl_xor(sum, m, 64);
            ssq += __shfl_xor(ssq, m, 64);
        }
        float zn = sqrtf(ssq);
        float mean = sum / (float)kD;
        float var = (ssq - (float)kD * mean * mean) / (float)(kD - 1); // ddof=1
        float sc = zn / (var + 1e-6f);
        sc = fminf(fmaxf(sc, 0.8f), 1.2f);
        if (lane == 0) sScale[r] = sc;
    }
    __syncthreads();

    // ---- z registers: wave w owns cols [w*64, w*64+64). layout (m=quad*4+rr, col) ----
    const int colbase = w * 64;
    float zreg[4][4], accR[4][4];
    #pragma unroll
    for (int nt = 0; nt < 4; ++nt)
        #pragma unroll
        for (int rr = 0; rr < 4; ++rr) {
            int m = quad * 4 + rr, col = colbase + nt * 16 + c;
            zreg[nt][rr] = bs2f(zin[(size_t)(r0 + m) * kD + col]) * sScale[m];
            accR[nt][rr] = 0.f;
        }
    // ---- initial arg = bf16(z0): wave w fills rows w and w+8 ----
    for (int r = w; r < 16; r += 8) {
        const s16* zrow = zin + (size_t)(r0 + r) * kD;
        float sc = sScale[r];
        s16* dst = sArg + r * 520 + lane * 8;
        #pragma unroll
        for (int j = 0; j < 8; ++j) dst[j] = f2bs(bs2f(zrow[lane * 8 + j]) * sc);
    }
    float b1v[2], b2v[2], b3v[4];
    #pragma unroll
    for (int nt = 0; nt < 2; ++nt) {
        b1v[nt] = bs2f(b1[w * 32 + nt * 16 + c]);
        b2v[nt] = bs2f(b2[w * 32 + nt * 16 + c]);
    }
    #pragma unroll
    for (int nt = 0; nt < 4; ++nt) b3v[nt] = bs2f(b3[colbase + nt * 16 + c]);

    // ---- W2 loop-resident fragments (64 VGPRs, loaded once) ----
    bf16x8 w2r[16];
    #pragma unroll
    for (int i = 0; i < 16; ++i) {
        int nt = i & 1, kk = i >> 1;
        w2r[i] = *(const bf16x8*)(W2 + (size_t)(w * 32 + nt * 16 + c) * kH + kk * 32 + quad * 8);
    }

    // per-lane element offsets into W1 / W3 (before nt/kk displacements)
    const int w1o = (w * 32 + c) * kD + quad * 8;
    const int w3o = (w * 64 + c) * kH + quad * 8;

    __syncthreads();

    #pragma unroll 1
    for (int t = 0; t < kT; ++t) {
        #pragma unroll 1
        for (int e = 0; e < 4; ++e) {
            // opaque the stream offsets so invariant weight loads cannot be
            // hoisted out of the loop (would need 300+ resident VGPRs -> spill)
            int ow1 = w1o, ow3 = w3o;
            asm volatile("" : "+v"(ow1), "+v"(ow3));
            const s16* W1p = W1 + ow1;
            const s16* W3p = W3 + ow3;

            // ---- batch-issue all 32 W1 fragments (i = kk*2 + nt) ----
            bf16x8 w1a[16], w1b[16];
            #pragma unroll
            for (int i = 0; i < 16; ++i) {
                int nt = i & 1, kk = i >> 1;                 // kk 0..7
                w1a[i] = *(const bf16x8*)(W1p + nt * 16 * kD + kk * 32);
            }
            #pragma unroll
            for (int i = 0; i < 16; ++i) {
                int nt = i & 1, kk = 8 + (i >> 1);           // kk 8..15
                w1b[i] = *(const bf16x8*)(W1p + nt * 16 * kD + kk * 32);
            }

            // GEMM1 chunk A (kk 0..7) — waits only on w1a, w1b still in flight
            f32x4 a1[2];
            a1[0] = {0.f, 0.f, 0.f, 0.f};
            a1[1] = {0.f, 0.f, 0.f, 0.f};
            #pragma unroll
            for (int kk = 0; kk < 8; ++kk) {
                bf16x8 av = *(const bf16x8*)(sArg + c * 520 + kk * 32 + quad * 8);
                a1[0] = mfma16(av, w1a[kk * 2 + 0], a1[0]);
                a1[1] = mfma16(av, w1a[kk * 2 + 1], a1[1]);
            }
            // GEMM1 chunk B (kk 8..15)
            #pragma unroll
            for (int kk = 0; kk < 8; ++kk) {
                bf16x8 av = *(const bf16x8*)(sArg + c * 520 + (8 + kk) * 32 + quad * 8);
                a1[0] = mfma16(av, w1b[kk * 2 + 0], a1[0]);
                a1[1] = mfma16(av, w1b[kk * 2 + 1], a1[1]);
            }
            #pragma unroll
            for (int nt = 0; nt < 2; ++nt)
                #pragma unroll
                for (int rr = 0; rr < 4; ++rr)
                    sH1[(quad * 4 + rr) * 264 + w * 32 + nt * 16 + c] = f2bs(gelu(a1[nt][rr] + b1v[nt]));
            __syncthreads();

            // ---- issue W3 chunk A now: drained by barrier 2 (shared wait) ----
            bf16x8 w3a[16];
            #pragma unroll
            for (int i = 0; i < 16; ++i) {
                int nt = i & 3, kk = i >> 2;                 // kk 0..3
                w3a[i] = *(const bf16x8*)(W3p + nt * 16 * kH + kk * 32);
            }

            // GEMM2 (W2 register-resident: zero load latency after barrier)
            f32x4 a2[2];
            a2[0] = {0.f, 0.f, 0.f, 0.f};
            a2[1] = {0.f, 0.f, 0.f, 0.f};
            #pragma unroll
            for (int kk = 0; kk < 8; ++kk) {
                bf16x8 av = *(const bf16x8*)(sH1 + c * 264 + kk * 32 + quad * 8);
                a2[0] = mfma16(av, w2r[kk * 2 + 0], a2[0]);
                a2[1] = mfma16(av, w2r[kk * 2 + 1], a2[1]);
            }
            // issue W3 chunk B during GEMM2 tail
            bf16x8 w3b[16];
            #pragma unroll
            for (int i = 0; i < 16; ++i) {
                int nt = i & 3, kk = 4 + (i >> 2);           // kk 4..7
                w3b[i] = *(const bf16x8*)(W3p + nt * 16 * kH + kk * 32);
            }
            #pragma unroll
            for (int nt = 0; nt < 2; ++nt)
                #pragma unroll
                for (int rr = 0; rr < 4; ++rr)
                    sH2[(quad * 4 + rr) * 264 + w * 32 + nt * 16 + c] = f2bs(gelu(a2[nt][rr] + b2v[nt]));
            __syncthreads();

            // GEMM3: out-cols colbase..colbase+63 (4 tiles), K=256
            f32x4 a3[4];
            #pragma unroll
            for (int nt = 0; nt < 4; ++nt) a3[nt] = {0.f, 0.f, 0.f, 0.f};
            #pragma unroll
            for (int kk = 0; kk < 4; ++kk) {
                bf16x8 av = *(const bf16x8*)(sH2 + c * 264 + kk * 32 + quad * 8);
                #pragma unroll
                for (int nt = 0; nt < 4; ++nt)
                    a3[nt] = mfma16(av, w3a[kk * 4 + nt], a3[nt]);
            }
            #pragma unroll
            for (int kk = 4; kk < 8; ++kk) {
                bf16x8 av = *(const bf16x8*)(sH2 + c * 264 + kk * 32 + quad * 8);
                #pragma unroll
                for (int nt = 0; nt < 4; ++nt)
                    a3[nt] = mfma16(av, w3b[(kk - 4) * 4 + nt], a3[nt]);
            }

            const float wsum = (e == 0 || e == 3) ? 1.f : 2.f;
            const float cstep = (e == 2) ? dt : hdt;
            #pragma unroll
            for (int nt = 0; nt < 4; ++nt) {
                #pragma unroll
                for (int rr = 0; rr < 4; ++rr) {
                    float fv = a3[nt][rr] + b3v[nt];
                    accR[nt][rr] += wsum * fv;
                    int m = quad * 4 + rr;
                    int col = colbase + nt * 16 + c;
                    float argv;
                    if (e < 3) {
                        argv = zreg[nt][rr] + cstep * fv;
                    } else {
                        float zn2 = zreg[nt][rr] + dt6 * accR[nt][rr];
                        zn2 = (zn2 != zn2) ? 0.f : zn2;  // NaN guard
                        zreg[nt][rr] = zn2;
                        accR[nt][rr] = 0.f;
                        argv = zn2;
                        stage[(size_t)(r0 + m) * kT * kD + (size_t)t * kD + col] = f2bs(zn2);
                    }
                    sArg[m * 520 + col] = f2bs(argv);
                }
            }
            __syncthreads();
        }
    }
}

// ============================================================================
// Attention kernel: 1024 blocks (one per batch row) x 256 threads (4 waves).
// Reads z_stack from stage; writes z_final to outp (bf16 or f32 per flag).
// Static LDS 55.3 KB. P and ctx overlay the dead Q buffer.
// ============================================================================
__global__ __launch_bounds__(256) void attn_kernel(
    const s16* __restrict__ zin,
    const s16* __restrict__ Wqkv, const s16* __restrict__ bqkv,
    const s16* __restrict__ Wo, const s16* __restrict__ bo,
    const s16* __restrict__ gm, const s16* __restrict__ bt,
    const s16* __restrict__ stage, void* __restrict__ outp,
    const int* __restrict__ flag, int mode)
{
    __shared__ __align__(16) s16 sQ[64 * 136];   // Q -> P -> ctx (per-wave rows)
    __shared__ __align__(16) s16 sK[64 * 136];
    __shared__ __align__(16) s16 sVT[128 * 72];  // V transposed [d][t]
    __shared__ __align__(16) s16 sMean[512];
    __shared__ __align__(16) s16 sZi[512];
    float* psum = (float*)sQ;                    // preamble overlay: [4][512] f32 (8 KB < 17.4 KB)

    const int tid = threadIdx.x;
    const int w = tid >> 6, lane = tid & 63, quad = lane >> 4, c = lane & 15;
    const int b = blockIdx.x;
    const int f32out = mode ? flag[0] : 0;
    const s16* zs = stage + (size_t)b * kT * kD;   // this block's z_stack [64][512]

    // ---- preamble: z_init row; column means of z_stack over T ----
    for (int i = tid; i < kD; i += 256) sZi[i] = zin[(size_t)b * kD + i];
    {
        float s[8] = {0, 0, 0, 0, 0, 0, 0, 0};
        const int phase = tid >> 6, cg = (tid & 63) * 8;
        for (int i = 0; i < 16; ++i) {
            int t = phase + 4 * i;
            bf16x8 v = *(const bf16x8*)(zs + (size_t)t * kD + cg);
            #pragma unroll
            for (int j = 0; j < 8; ++j) s[j] += bs2f(v[j]);
        }
        #pragma unroll
        for (int j = 0; j < 8; ++j) psum[phase * kD + cg + j] = s[j];
    }
    __syncthreads();
    for (int col = tid; col < kD; col += 256) {
        float m = (psum[col] + psum[kD + col] + psum[2 * kD + col] + psum[3 * kD + col]) * (1.f / 64.f);
        sMean[col] = f2bs(m);
    }
    __syncthreads();

    // ---- A-fragments of z_dc for this wave's 16 rows (t = w*16 + c) ----
    bf16x8 afrag[16];
    #pragma unroll
    for (int kk = 0; kk < 16; ++kk) {
        int k0 = kk * 32 + quad * 8;
        bf16x8 zv = *(const bf16x8*)(zs + (size_t)(w * 16 + c) * kD + k0);
        bf16x8 o;
        #pragma unroll
        for (int j = 0; j < 8; ++j) {
            float zd = bs2f(zv[j]) - 0.05f * (bs2f(sMean[k0 + j]) - bs2f(sZi[k0 + j]));
            o[j] = f2bs(zd);
        }
        afrag[kk] = o;
    }

    f32x4 xacc[32];
    #pragma unroll
    for (int nt = 0; nt < 32; ++nt) xacc[nt] = {0.f, 0.f, 0.f, 0.f};

    const float iscl = 0.08838834764831845f;  // 1/sqrt(128)

    for (int h = 0; h < 4; ++h) {
        __syncthreads();  // protect sQ/sK/sVT rewrite vs prior head's readers
        // ---- qkv for head h: mat 0=Q, 1=K, 2=V ----
        for (int mat = 0; mat < 3; ++mat) {
            f32x4 acc[8];
            #pragma unroll
            for (int nt = 0; nt < 8; ++nt) acc[nt] = {0.f, 0.f, 0.f, 0.f};
            const s16* Wbase = Wqkv + (size_t)(mat * 512 + h * 128 + c) * kD + quad * 8;
            #pragma unroll
            for (int kk = 0; kk < 16; ++kk) {
                bf16x8 a = afrag[kk];
                #pragma unroll
                for (int nt = 0; nt < 8; ++nt) {
                    bf16x8 bb = *(const bf16x8*)(Wbase + (size_t)(nt * 16) * kD + kk * 32);
                    acc[nt] = mfma16(a, bb, acc[nt]);
                }
            }
            #pragma unroll
            for (int nt = 0; nt < 8; ++nt)
                #pragma unroll
                for (int rr = 0; rr < 4; ++rr) {
                    int n = h * 128 + nt * 16 + c;
                    float v = acc[nt][rr] + bs2f(bqkv[mat * 512 + n]);
                    int trow = w * 16 + quad * 4 + rr, dcol = nt * 16 + c;
                    if (mat == 0)      sQ[trow * 136 + dcol] = f2bs(v);
                    else if (mat == 1) sK[trow * 136 + dcol] = f2bs(v);
                    else               sVT[dcol * 72 + trow] = f2bs(v);
                }
        }
        __syncthreads();

        // ---- S = Q K^T (wave's 16 q-rows x 64 k-cols) ----
        f32x4 sfr[4];
        #pragma unroll
        for (int nt = 0; nt < 4; ++nt) sfr[nt] = {0.f, 0.f, 0.f, 0.f};
        #pragma unroll
        for (int kk = 0; kk < 4; ++kk) {
            bf16x8 a = *(const bf16x8*)(sQ + (w * 16 + c) * 136 + kk * 32 + quad * 8);
            #pragma unroll
            for (int nt = 0; nt < 4; ++nt) {
                bf16x8 bb = *(const bf16x8*)(sK + (nt * 16 + c) * 136 + kk * 32 + quad * 8);
                sfr[nt] = mfma16(a, bb, sfr[nt]);
            }
        }
        // ---- softmax along k (within quad: 16 lanes x 4 regs) ----
        #pragma unroll
        for (int rr = 0; rr < 4; ++rr) {
            float v[4];
            #pragma unroll
            for (int nt = 0; nt < 4; ++nt) v[nt] = sfr[nt][rr] * iscl;
            float mx = fmaxf(fmaxf(v[0], v[1]), fmaxf(v[2], v[3]));
            for (int m = 1; m < 16; m <<= 1) mx = fmaxf(mx, __shfl_xor(mx, m, 64));
            float sm = 0.f;
            #pragma unroll
            for (int nt = 0; nt < 4; ++nt) { v[nt] = __expf(v[nt] - mx); sm += v[nt]; }
            for (int m = 1; m < 16; m <<= 1) sm += __shfl_xor(sm, m, 64);
            float inv = 1.0f / sm;
            // P overlays dead Q (own rows only; no wave reads another wave's Q rows)
            #pragma unroll
            for (int nt = 0; nt < 4; ++nt)
                sQ[(w * 16 + quad * 4 + rr) * 136 + nt * 16 + c] = f2bs(v[nt] * inv);
        }
        // ---- ctx_h = P @ V  (K=64) ----
        f32x4 o[8];
        #pragma unroll
        for (int nt = 0; nt < 8; ++nt) o[nt] = {0.f, 0.f, 0.f, 0.f};
        #pragma unroll
        for (int kk = 0; kk < 2; ++kk) {
            bf16x8 a = *(const bf16x8*)(sQ + (w * 16 + c) * 136 + kk * 32 + quad * 8);
            #pragma unroll
            for (int nt = 0; nt < 8; ++nt) {
                bf16x8 bb = *(const bf16x8*)(sVT + (nt * 16 + c) * 72 + kk * 32 + quad * 8);
                o[nt] = mfma16(a, bb, o[nt]);
            }
        }
        // ctx_h -> sQ (own rows; P consumed)
        #pragma unroll
        for (int nt = 0; nt < 8; ++nt)
            #pragma unroll
            for (int rr = 0; rr < 4; ++rr)
                sQ[(w * 16 + quad * 4 + rr) * 136 + nt * 16 + c] = f2bs(o[nt][rr]);
        // ---- out-proj partial: x += ctx_h @ Wo[:, h*128:+128]^T ----
        #pragma unroll
        for (int kk = 0; kk < 4; ++kk) {
            bf16x8 a = *(const bf16x8*)(sQ + (w * 16 + c) * 136 + kk * 32 + quad * 8);
            #pragma unroll
            for (int nt = 0; nt < 32; ++nt) {
                bf16x8 bb = *(const bf16x8*)(Wo + (size_t)(nt * 16 + c) * kD + h * 128 + kk * 32 + quad * 8);
                xacc[nt] = mfma16(a, bb, xacc[nt]);
            }
        }
    }

    // ---- epilogue: x = z_dc + att_out + bo; LayerNorm; store ----
    float sum[4] = {0, 0, 0, 0}, ssq[4] = {0, 0, 0, 0};
    #pragma unroll
    for (int nt = 0; nt < 32; ++nt)
        #pragma unroll
        for (int rr = 0; rr < 4; ++rr) {
            int trow = w * 16 + quad * 4 + rr;
            int col = nt * 16 + c;
            float zd = bs2f(zs[(size_t)trow * kD + col]) - 0.05f * (bs2f(sMean[col]) - bs2f(sZi[col]));
            float x = xacc[nt][rr] + bs2f(bo[col]) + zd;
            xacc[nt][rr] = x;
            sum[rr] += x; ssq[rr] += x * x;
        }
    float mu[4], rstd[4];
    #pragma unroll
    for (int rr = 0; rr < 4; ++rr) {
        float s = sum[rr], q = ssq[rr];
        for (int m = 1; m < 16; m <<= 1) { s += __shfl_xor(s, m, 64); q += __shfl_xor(q, m, 64); }
        float mm = s / (float)kD;
        float var = q / (float)kD - mm * mm;   // biased, eps 1e-5
        mu[rr] = mm;
        rstd[rr] = rsqrtf(var + 1e-5f);
    }
    #pragma unroll
    for (int nt = 0; nt < 32; ++nt)
        #pragma unroll
        for (int rr = 0; rr < 4; ++rr) {
            int trow = w * 16 + quad * 4 + rr;
            int col = nt * 16 + c;
            float v = (xacc[nt][rr] - mu[rr]) * rstd[rr] * bs2f(gm[col]) + bs2f(bt[col]);
            v = (v != v) ? 0.f : v;
            size_t idx = ((size_t)b * kT + trow) * kD + col;
            if (f32out) ((float*)outp)[idx] = v;
            else        ((s16*)outp)[idx] = f2bs(v);
        }
}

extern "C" void kernel_launch(void* const* d_in, const int* in_sizes, int n_in,
                              void* d_out, int out_size, void* d_ws, size_t ws_size,
                              hipStream_t stream) {
    (void)in_sizes; (void)n_in; (void)out_size;
    const size_t kStageElems = (size_t)kB * kT * kD;
    const size_t kNeed = 16 + (size_t)kTotalConv * 2 + kStageElems * 2;   // ~70.9 MB

    const s16* p[NSEG];
    s16* stage;
    void* outp = d_out;
    const int* flag = nullptr;
    int mode = 0;

    if (ws_size >= kNeed) {
        int* flg = (int*)d_ws;
        s16* conv = (s16*)((char*)d_ws + 16);
        stage = (s16*)((char*)d_ws + 16 + (size_t)kTotalConv * 2);
        detect_kernel<<<dim3(1), dim3(64), 0, stream>>>((const unsigned*)d_in[1], flg);
        ConvArgs ca;
        for (int i = 0; i < NSEG; ++i) ca.src[i] = d_in[i];
        convert_kernel<<<dim3(512), dim3(256), 0, stream>>>(ca, conv, flg);
        for (int i = 0; i < NSEG; ++i) p[i] = conv + kOff[i];
        flag = flg;
        mode = 1;
    } else {
        for (int i = 0; i < NSEG; ++i) p[i] = (const s16*)d_in[i];
        stage = (s16*)d_out;   // in-place staging (bf16 assumed)
    }

    ode_kernel<<<dim3(64), dim3(512), 0, stream>>>(
        p[0], p[1], p[2], p[3], p[4], p[5], p[6], p[7], stage);
    attn_kernel<<<dim3(kB), dim3(256), 0, stream>>>(
        p[0], p[8], p[9], p[10], p[11], p[12], p[13], stage, outp, flag, mode);
}

// Round 6
// 6121.732 us; speedup vs baseline: 1.0606x; 1.0606x over previous
//
#include <hip/hip_runtime.h>

typedef short s16;
typedef short bf16x8 __attribute__((ext_vector_type(8)));
typedef float f32x4 __attribute__((ext_vector_type(4)));

constexpr int kB = 1024, kT = 64, kD = 512, kH = 256;
constexpr int NSEG = 14;
// element counts per input (setup_inputs order) and exclusive prefix offsets
// z_init t  W1     b1  W2    b2  W3     b3  Wqkv   bqkv Wo     bo  gamma beta
// 524288 64 131072 256 65536 256 131072 512 786432 1536 262144 512 512   512
constexpr int kOff[NSEG] = {0, 524288, 524352, 655424, 655680, 721216, 721472,
                            852544, 853056, 1639488, 1641024, 1903168, 1903680, 1904192};
constexpr int kTotalConv = 1904704;

__device__ __forceinline__ float bs2f(s16 s) {
    return __uint_as_float(((unsigned)(unsigned short)s) << 16);
}
__device__ __forceinline__ s16 f2bs(float f) {
    unsigned u = __float_as_uint(f);
    unsigned r = (u + 0x7fffu + ((u >> 16) & 1u)) >> 16;
    return (s16)r;
}
__device__ __forceinline__ f32x4 mfma16(bf16x8 a, bf16x8 b, f32x4 c) {
    return __builtin_amdgcn_mfma_f32_16x16x32_bf16(a, b, c, 0, 0, 0);
}
__device__ __forceinline__ float gelu(float x) {
    return 0.5f * x * (1.0f + erff(x * 0.70710678118654752f));
}

// Forced async weight load: volatile asm cannot be sunk/rematerialized by LLVM.
// OFF must be a literal (13-bit signed imm). Drain with VMWAIT0 before use.
#define GLD(dst, ptr, OFF) \
    asm volatile("global_load_dwordx4 %0, %1, off offset:" #OFF : "=v"(dst) : "v"(ptr))
// Rule #18: sched_barrier(0) required — "memory" clobber does not stop
// register-only MFMAs from being hoisted past the waitcnt.
#define VMWAIT0 do { asm volatile("s_waitcnt vmcnt(0)" ::: "memory"); \
                     __builtin_amdgcn_sched_barrier(0); } while (0)

// ---------------------------------------------------------------------------
// dtype detect: t_steps[0..1] as one 32-bit word. bf16: [0, bf16(0.05)] ->
// 0x3D4D0000 != 0.  f32: first float 0.0f -> 0x00000000.
// flag = 1 means inputs are f32.
// ---------------------------------------------------------------------------
__global__ void detect_kernel(const unsigned* __restrict__ ts, int* __restrict__ flag) {
    if (threadIdx.x == 0 && blockIdx.x == 0) flag[0] = (ts[0] == 0u) ? 1 : 0;
}

struct ConvArgs { const void* src[NSEG]; };

__global__ __launch_bounds__(256) void convert_kernel(ConvArgs a, s16* __restrict__ dst,
                                                      const int* __restrict__ flag) {
    const int f = flag[0];
    for (int i = blockIdx.x * 256 + threadIdx.x; i < kTotalConv; i += gridDim.x * 256) {
        int s = 0;
        #pragma unroll
        for (int j = 1; j < NSEG; ++j) if (i >= kOff[j]) s = j;
        int local = i - kOff[s];
        s16 v;
        if (f) v = f2bs(((const float*)a.src[s])[local]);
        else   v = ((const s16*)a.src[s])[local];
        dst[i] = v;
    }
}

// ============================================================================
// ODE kernel: 64 blocks x 512 threads (8 waves). Block owns 16 rows of B.
// Wave w owns h-cols [w*32,w*32+32) for GEMM1/2 and out-cols [w*64,w*64+64)
// for GEMM3.  Weight streaming is forced into batched async form with
// volatile-asm global_load_dwordx4 (compiler cannot sink/remat them):
//   W2: asm-preloaded ONCE into 64 persistent VGPRs.
//   W1: 2 batches of 16 per eval (issue 16 -> vmcnt(0) -> 16 MFMAs).
//   W3: batch A issued during GEMM2 (flight hides under compute+barrier),
//       batch B issued during GEMM3's first half.
// Per-eval cost should approach the per-CU L1-port floor (~1.25 MB/eval
// through ~64 B/cy ≈ 4.3 µs/eval) instead of 80 serialized ~500cy chains.
// Peak live ≈ 195 VGPR < 256 cap of __launch_bounds__(512,2). No scratch.
// ============================================================================
__global__ __launch_bounds__(512, 2) void ode_kernel(
    const s16* __restrict__ zin, const s16* __restrict__ ts,
    const s16* __restrict__ W1, const s16* __restrict__ b1,
    const s16* __restrict__ W2, const s16* __restrict__ b2,
    const s16* __restrict__ W3, const s16* __restrict__ b3,
    s16* __restrict__ stage)
{
    __shared__ __align__(16) s16 sArg[16 * 520];   // [16][520]
    __shared__ __align__(16) s16 sH1[16 * 264];    // [16][264]
    __shared__ __align__(16) s16 sH2[16 * 264];    // [16][264]
    __shared__ float sScale[16];

    const int tid = threadIdx.x;
    const int w = tid >> 6;          // wave 0..7
    const int lane = tid & 63;
    const int quad = lane >> 4;
    const int c = lane & 15;
    const int r0 = blockIdx.x * 16;

    const float dt  = bs2f(ts[1]) - bs2f(ts[0]);
    const float hdt = 0.5f * dt;
    const float dt6 = dt / 6.0f;

    // ---- per-row adaptive scale (wave w handles rows w and w+8) ----
    for (int r = w; r < 16; r += 8) {
        const s16* zrow = zin + (size_t)(r0 + r) * kD;
        float sum = 0.f, ssq = 0.f;
        for (int i = 0; i < 8; ++i) {
            float v = bs2f(zrow[lane + 64 * i]);
            sum += v; ssq += v * v;
        }
        for (int m = 1; m < 64; m <<= 1) {
            sum += __shfl_xor(sum, m, 64);
            ssq += __shfl_xor(ssq, m, 64);
        }
        float zn = sqrtf(ssq);
        float mean = sum / (float)kD;
        float var = (ssq - (float)kD * mean * mean) / (float)(kD - 1); // ddof=1
        float sc = zn / (var + 1e-6f);
        sc = fminf(fmaxf(sc, 0.8f), 1.2f);
        if (lane == 0) sScale[r] = sc;
    }
    __syncthreads();

    // ---- z registers: wave w owns cols [w*64, w*64+64). layout (m=quad*4+rr, col) ----
    const int colbase = w * 64;
    float zreg[4][4], accR[4][4];
    #pragma unroll
    for (int nt = 0; nt < 4; ++nt)
        #pragma unroll
        for (int rr = 0; rr < 4; ++rr) {
            int m = quad * 4 + rr, col = colbase + nt * 16 + c;
            zreg[nt][rr] = bs2f(zin[(size_t)(r0 + m) * kD + col]) * sScale[m];
            accR[nt][rr] = 0.f;
        }
    // ---- initial arg = bf16(z0): wave w fills rows w and w+8 ----
    for (int r = w; r < 16; r += 8) {
        const s16* zrow = zin + (size_t)(r0 + r) * kD;
        float sc = sScale[r];
        s16* dst = sArg + r * 520 + lane * 8;
        #pragma unroll
        for (int j = 0; j < 8; ++j) dst[j] = f2bs(bs2f(zrow[lane * 8 + j]) * sc);
    }
    float b1v[2], b2v[2], b3v[4];
    #pragma unroll
    for (int nt = 0; nt < 2; ++nt) {
        b1v[nt] = bs2f(b1[w * 32 + nt * 16 + c]);
        b2v[nt] = bs2f(b2[w * 32 + nt * 16 + c]);
    }
    #pragma unroll
    for (int nt = 0; nt < 4; ++nt) b3v[nt] = bs2f(b3[colbase + nt * 16 + c]);

    // ---- per-lane weight base pointers (element units; asm offsets in bytes) ----
    const s16* w1p0 = W1 + (size_t)(w * 32 + c) * kD + quad * 8;   // nt=0 rows
    const s16* w1p1 = w1p0 + 16 * kD;                              // nt=1 rows
    const s16* w2p0 = W2 + (size_t)(w * 32 + c) * kH + quad * 8;
    const s16* w2p1 = w2p0 + 16 * kH;
    const s16* w3p0 = W3 + (size_t)(w * 64 + c) * kH + quad * 8;
    const s16* w3p1 = w3p0 + 16 * kH;
    const s16* w3p2 = w3p0 + 32 * kH;
    const s16* w3p3 = w3p0 + 48 * kH;

    // ---- W2 truly resident: forced asm loads, kept live across the t-loop ----
    bf16x8 w2r[16];   // w2r[kk*2+nt]
    GLD(w2r[0],  w2p0, 0);   GLD(w2r[1],  w2p1, 0);
    GLD(w2r[2],  w2p0, 64);  GLD(w2r[3],  w2p1, 64);
    GLD(w2r[4],  w2p0, 128); GLD(w2r[5],  w2p1, 128);
    GLD(w2r[6],  w2p0, 192); GLD(w2r[7],  w2p1, 192);
    GLD(w2r[8],  w2p0, 256); GLD(w2r[9],  w2p1, 256);
    GLD(w2r[10], w2p0, 320); GLD(w2r[11], w2p1, 320);
    GLD(w2r[12], w2p0, 384); GLD(w2r[13], w2p1, 384);
    GLD(w2r[14], w2p0, 448); GLD(w2r[15], w2p1, 448);
    VMWAIT0;

    __syncthreads();

    #pragma unroll 1
    for (int t = 0; t < kT; ++t) {
        #pragma unroll 1
        for (int e = 0; e < 4; ++e) {
            // ================= Phase 1: GEMM1 (K=512), W1 streamed ==========
            f32x4 a1n0 = {0.f, 0.f, 0.f, 0.f}, a1n1 = {0.f, 0.f, 0.f, 0.f};
            {
                bf16x8 wf[16];   // wf[kk*2+nt]
                // batch A: kk 0..7 (byte offsets kk*64)
                GLD(wf[0],  w1p0, 0);   GLD(wf[1],  w1p1, 0);
                GLD(wf[2],  w1p0, 64);  GLD(wf[3],  w1p1, 64);
                GLD(wf[4],  w1p0, 128); GLD(wf[5],  w1p1, 128);
                GLD(wf[6],  w1p0, 192); GLD(wf[7],  w1p1, 192);
                GLD(wf[8],  w1p0, 256); GLD(wf[9],  w1p1, 256);
                GLD(wf[10], w1p0, 320); GLD(wf[11], w1p1, 320);
                GLD(wf[12], w1p0, 384); GLD(wf[13], w1p1, 384);
                GLD(wf[14], w1p0, 448); GLD(wf[15], w1p1, 448);
                VMWAIT0;
                #pragma unroll
                for (int kk = 0; kk < 8; ++kk) {
                    bf16x8 av = *(const bf16x8*)(sArg + c * 520 + kk * 32 + quad * 8);
                    a1n0 = mfma16(av, wf[kk * 2 + 0], a1n0);
                    a1n1 = mfma16(av, wf[kk * 2 + 1], a1n1);
                }
                // batch B: kk 8..15 (byte offsets 512..960), reuse wf[]
                GLD(wf[0],  w1p0, 512); GLD(wf[1],  w1p1, 512);
                GLD(wf[2],  w1p0, 576); GLD(wf[3],  w1p1, 576);
                GLD(wf[4],  w1p0, 640); GLD(wf[5],  w1p1, 640);
                GLD(wf[6],  w1p0, 704); GLD(wf[7],  w1p1, 704);
                GLD(wf[8],  w1p0, 768); GLD(wf[9],  w1p1, 768);
                GLD(wf[10], w1p0, 832); GLD(wf[11], w1p1, 832);
                GLD(wf[12], w1p0, 896); GLD(wf[13], w1p1, 896);
                GLD(wf[14], w1p0, 960); GLD(wf[15], w1p1, 960);
                VMWAIT0;
                #pragma unroll
                for (int kk = 0; kk < 8; ++kk) {
                    bf16x8 av = *(const bf16x8*)(sArg + c * 520 + (8 + kk) * 32 + quad * 8);
                    a1n0 = mfma16(av, wf[kk * 2 + 0], a1n0);
                    a1n1 = mfma16(av, wf[kk * 2 + 1], a1n1);
                }
            }
            sH1[(quad * 4 + 0) * 264 + w * 32 + 0 * 16 + c] = f2bs(gelu(a1n0[0] + b1v[0]));
            sH1[(quad * 4 + 1) * 264 + w * 32 + 0 * 16 + c] = f2bs(gelu(a1n0[1] + b1v[0]));
            sH1[(quad * 4 + 2) * 264 + w * 32 + 0 * 16 + c] = f2bs(gelu(a1n0[2] + b1v[0]));
            sH1[(quad * 4 + 3) * 264 + w * 32 + 0 * 16 + c] = f2bs(gelu(a1n0[3] + b1v[0]));
            sH1[(quad * 4 + 0) * 264 + w * 32 + 1 * 16 + c] = f2bs(gelu(a1n1[0] + b1v[1]));
            sH1[(quad * 4 + 1) * 264 + w * 32 + 1 * 16 + c] = f2bs(gelu(a1n1[1] + b1v[1]));
            sH1[(quad * 4 + 2) * 264 + w * 32 + 1 * 16 + c] = f2bs(gelu(a1n1[2] + b1v[1]));
            sH1[(quad * 4 + 3) * 264 + w * 32 + 1 * 16 + c] = f2bs(gelu(a1n1[3] + b1v[1]));
            __syncthreads();

            // ================= Phase 2: GEMM2 (W2 resident) =================
            // issue W3 batch A (kk 0..3, all 4 nt) — flight hides under GEMM2
            bf16x8 w3x[16];   // w3x[kk*4+nt]
            GLD(w3x[0],  w3p0, 0);   GLD(w3x[1],  w3p1, 0);
            GLD(w3x[2],  w3p2, 0);   GLD(w3x[3],  w3p3, 0);
            GLD(w3x[4],  w3p0, 64);  GLD(w3x[5],  w3p1, 64);
            GLD(w3x[6],  w3p2, 64);  GLD(w3x[7],  w3p3, 64);
            GLD(w3x[8],  w3p0, 128); GLD(w3x[9],  w3p1, 128);
            GLD(w3x[10], w3p2, 128); GLD(w3x[11], w3p3, 128);
            GLD(w3x[12], w3p0, 192); GLD(w3x[13], w3p1, 192);
            GLD(w3x[14], w3p2, 192); GLD(w3x[15], w3p3, 192);

            f32x4 a2n0 = {0.f, 0.f, 0.f, 0.f}, a2n1 = {0.f, 0.f, 0.f, 0.f};
            #pragma unroll
            for (int kk = 0; kk < 8; ++kk) {
                bf16x8 av = *(const bf16x8*)(sH1 + c * 264 + kk * 32 + quad * 8);
                a2n0 = mfma16(av, w2r[kk * 2 + 0], a2n0);
                a2n1 = mfma16(av, w2r[kk * 2 + 1], a2n1);
            }
            sH2[(quad * 4 + 0) * 264 + w * 32 + 0 * 16 + c] = f2bs(gelu(a2n0[0] + b2v[0]));
            sH2[(quad * 4 + 1) * 264 + w * 32 + 0 * 16 + c] = f2bs(gelu(a2n0[1] + b2v[0]));
            sH2[(quad * 4 + 2) * 264 + w * 32 + 0 * 16 + c] = f2bs(gelu(a2n0[2] + b2v[0]));
            sH2[(quad * 4 + 3) * 264 + w * 32 + 0 * 16 + c] = f2bs(gelu(a2n0[3] + b2v[0]));
            sH2[(quad * 4 + 0) * 264 + w * 32 + 1 * 16 + c] = f2bs(gelu(a2n1[0] + b2v[1]));
            sH2[(quad * 4 + 1) * 264 + w * 32 + 1 * 16 + c] = f2bs(gelu(a2n1[1] + b2v[1]));
            sH2[(quad * 4 + 2) * 264 + w * 32 + 1 * 16 + c] = f2bs(gelu(a2n1[2] + b2v[1]));
            sH2[(quad * 4 + 3) * 264 + w * 32 + 1 * 16 + c] = f2bs(gelu(a2n1[3] + b2v[1]));
            __syncthreads();

            // ================= Phase 3: GEMM3 (K=256) =======================
            VMWAIT0;   // w3 batch A ready (explicit: compiler doesn't track asm loads)
            f32x4 a3[4];
            #pragma unroll
            for (int nt = 0; nt < 4; ++nt) a3[nt] = {0.f, 0.f, 0.f, 0.f};
            #pragma unroll
            for (int kk = 0; kk < 4; ++kk) {
                bf16x8 av = *(const bf16x8*)(sH2 + c * 264 + kk * 32 + quad * 8);
                #pragma unroll
                for (int nt = 0; nt < 4; ++nt)
                    a3[nt] = mfma16(av, w3x[kk * 4 + nt], a3[nt]);
            }
            // batch B: kk 4..7 (byte offsets 256..448), reuse w3x[]
            GLD(w3x[0],  w3p0, 256); GLD(w3x[1],  w3p1, 256);
            GLD(w3x[2],  w3p2, 256); GLD(w3x[3],  w3p3, 256);
            GLD(w3x[4],  w3p0, 320); GLD(w3x[5],  w3p1, 320);
            GLD(w3x[6],  w3p2, 320); GLD(w3x[7],  w3p3, 320);
            GLD(w3x[8],  w3p0, 384); GLD(w3x[9],  w3p1, 384);
            GLD(w3x[10], w3p2, 384); GLD(w3x[11], w3p3, 384);
            GLD(w3x[12], w3p0, 448); GLD(w3x[13], w3p1, 448);
            GLD(w3x[14], w3p2, 448); GLD(w3x[15], w3p3, 448);
            VMWAIT0;
            #pragma unroll
            for (int kk = 0; kk < 4; ++kk) {
                bf16x8 av = *(const bf16x8*)(sH2 + c * 264 + (4 + kk) * 32 + quad * 8);
                #pragma unroll
                for (int nt = 0; nt < 4; ++nt)
                    a3[nt] = mfma16(av, w3x[kk * 4 + nt], a3[nt]);
            }

            const float wsum = (e == 0 || e == 3) ? 1.f : 2.f;
            const float cstep = (e == 2) ? dt : hdt;
            #pragma unroll
            for (int nt = 0; nt < 4; ++nt) {
                #pragma unroll
                for (int rr = 0; rr < 4; ++rr) {
                    float fv = a3[nt][rr] + b3v[nt];
                    accR[nt][rr] += wsum * fv;
                    int m = quad * 4 + rr;
                    int col = colbase + nt * 16 + c;
                    float argv;
                    if (e < 3) {
                        argv = zreg[nt][rr] + cstep * fv;
                    } else {
                        float zn2 = zreg[nt][rr] + dt6 * accR[nt][rr];
                        zn2 = (zn2 != zn2) ? 0.f : zn2;  // NaN guard
                        zreg[nt][rr] = zn2;
                        accR[nt][rr] = 0.f;
                        argv = zn2;
                        stage[(size_t)(r0 + m) * kT * kD + (size_t)t * kD + col] = f2bs(zn2);
                    }
                    sArg[m * 520 + col] = f2bs(argv);
                }
            }
            __syncthreads();
        }
    }
}

// ============================================================================
// Attention kernel: 1024 blocks (one per batch row) x 256 threads (4 waves).
// Reads z_stack from stage; writes z_final to outp (bf16 or f32 per flag).
// Static LDS 55.3 KB. P and ctx overlay the dead Q buffer.
// ============================================================================
__global__ __launch_bounds__(256) void attn_kernel(
    const s16* __restrict__ zin,
    const s16* __restrict__ Wqkv, const s16* __restrict__ bqkv,
    const s16* __restrict__ Wo, const s16* __restrict__ bo,
    const s16* __restrict__ gm, const s16* __restrict__ bt,
    const s16* __restrict__ stage, void* __restrict__ outp,
    const int* __restrict__ flag, int mode)
{
    __shared__ __align__(16) s16 sQ[64 * 136];   // Q -> P -> ctx (per-wave rows)
    __shared__ __align__(16) s16 sK[64 * 136];
    __shared__ __align__(16) s16 sVT[128 * 72];  // V transposed [d][t]
    __shared__ __align__(16) s16 sMean[512];
    __shared__ __align__(16) s16 sZi[512];
    float* psum = (float*)sQ;                    // preamble overlay: [4][512] f32 (8 KB < 17.4 KB)

    const int tid = threadIdx.x;
    const int w = tid >> 6, lane = tid & 63, quad = lane >> 4, c = lane & 15;
    const int b = blockIdx.x;
    const int f32out = mode ? flag[0] : 0;
    const s16* zs = stage + (size_t)b * kT * kD;   // this block's z_stack [64][512]

    // ---- preamble: z_init row; column means of z_stack over T ----
    for (int i = tid; i < kD; i += 256) sZi[i] = zin[(size_t)b * kD + i];
    {
        float s[8] = {0, 0, 0, 0, 0, 0, 0, 0};
        const int phase = tid >> 6, cg = (tid & 63) * 8;
        for (int i = 0; i < 16; ++i) {
            int t = phase + 4 * i;
            bf16x8 v = *(const bf16x8*)(zs + (size_t)t * kD + cg);
            #pragma unroll
            for (int j = 0; j < 8; ++j) s[j] += bs2f(v[j]);
        }
        #pragma unroll
        for (int j = 0; j < 8; ++j) psum[phase * kD + cg + j] = s[j];
    }
    __syncthreads();
    for (int col = tid; col < kD; col += 256) {
        float m = (psum[col] + psum[kD + col] + psum[2 * kD + col] + psum[3 * kD + col]) * (1.f / 64.f);
        sMean[col] = f2bs(m);
    }
    __syncthreads();

    // ---- A-fragments of z_dc for this wave's 16 rows (t = w*16 + c) ----
    bf16x8 afrag[16];
    #pragma unroll
    for (int kk = 0; kk < 16; ++kk) {
        int k0 = kk * 32 + quad * 8;
        bf16x8 zv = *(const bf16x8*)(zs + (size_t)(w * 16 + c) * kD + k0);
        bf16x8 o;
        #pragma unroll
        for (int j = 0; j < 8; ++j) {
            float zd = bs2f(zv[j]) - 0.05f * (bs2f(sMean[k0 + j]) - bs2f(sZi[k0 + j]));
            o[j] = f2bs(zd);
        }
        afrag[kk] = o;
    }

    f32x4 xacc[32];
    #pragma unroll
    for (int nt = 0; nt < 32; ++nt) xacc[nt] = {0.f, 0.f, 0.f, 0.f};

    const float iscl = 0.08838834764831845f;  // 1/sqrt(128)

    for (int h = 0; h < 4; ++h) {
        __syncthreads();  // protect sQ/sK/sVT rewrite vs prior head's readers
        // ---- qkv for head h: mat 0=Q, 1=K, 2=V ----
        for (int mat = 0; mat < 3; ++mat) {
            f32x4 acc[8];
            #pragma unroll
            for (int nt = 0; nt < 8; ++nt) acc[nt] = {0.f, 0.f, 0.f, 0.f};
            const s16* Wbase = Wqkv + (size_t)(mat * 512 + h * 128 + c) * kD + quad * 8;
            #pragma unroll
            for (int kk = 0; kk < 16; ++kk) {
                bf16x8 a = afrag[kk];
                #pragma unroll
                for (int nt = 0; nt < 8; ++nt) {
                    bf16x8 bb = *(const bf16x8*)(Wbase + (size_t)(nt * 16) * kD + kk * 32);
                    acc[nt] = mfma16(a, bb, acc[nt]);
                }
            }
            #pragma unroll
            for (int nt = 0; nt < 8; ++nt)
                #pragma unroll
                for (int rr = 0; rr < 4; ++rr) {
                    int n = h * 128 + nt * 16 + c;
                    float v = acc[nt][rr] + bs2f(bqkv[mat * 512 + n]);
                    int trow = w * 16 + quad * 4 + rr, dcol = nt * 16 + c;
                    if (mat == 0)      sQ[trow * 136 + dcol] = f2bs(v);
                    else if (mat == 1) sK[trow * 136 + dcol] = f2bs(v);
                    else               sVT[dcol * 72 + trow] = f2bs(v);
                }
        }
        __syncthreads();

        // ---- S = Q K^T (wave's 16 q-rows x 64 k-cols) ----
        f32x4 sfr[4];
        #pragma unroll
        for (int nt = 0; nt < 4; ++nt) sfr[nt] = {0.f, 0.f, 0.f, 0.f};
        #pragma unroll
        for (int kk = 0; kk < 4; ++kk) {
            bf16x8 a = *(const bf16x8*)(sQ + (w * 16 + c) * 136 + kk * 32 + quad * 8);
            #pragma unroll
            for (int nt = 0; nt < 4; ++nt) {
                bf16x8 bb = *(const bf16x8*)(sK + (nt * 16 + c) * 136 + kk * 32 + quad * 8);
                sfr[nt] = mfma16(a, bb, sfr[nt]);
            }
        }
        // ---- softmax along k (within quad: 16 lanes x 4 regs) ----
        #pragma unroll
        for (int rr = 0; rr < 4; ++rr) {
            float v[4];
            #pragma unroll
            for (int nt = 0; nt < 4; ++nt) v[nt] = sfr[nt][rr] * iscl;
            float mx = fmaxf(fmaxf(v[0], v[1]), fmaxf(v[2], v[3]));
            for (int m = 1; m < 16; m <<= 1) mx = fmaxf(mx, __shfl_xor(mx, m, 64));
            float sm = 0.f;
            #pragma unroll
            for (int nt = 0; nt < 4; ++nt) { v[nt] = __expf(v[nt] - mx); sm += v[nt]; }
            for (int m = 1; m < 16; m <<= 1) sm += __shfl_xor(sm, m, 64);
            float inv = 1.0f / sm;
            // P overlays dead Q (own rows only; no wave reads another wave's Q rows)
            #pragma unroll
            for (int nt = 0; nt < 4; ++nt)
                sQ[(w * 16 + quad * 4 + rr) * 136 + nt * 16 + c] = f2bs(v[nt] * inv);
        }
        // ---- ctx_h = P @ V  (K=64) ----
        f32x4 o[8];
        #pragma unroll
        for (int nt = 0; nt < 8; ++nt) o[nt] = {0.f, 0.f, 0.f, 0.f};
        #pragma unroll
        for (int kk = 0; kk < 2; ++kk) {
            bf16x8 a = *(const bf16x8*)(sQ + (w * 16 + c) * 136 + kk * 32 + quad * 8);
            #pragma unroll
            for (int nt = 0; nt < 8; ++nt) {
                bf16x8 bb = *(const bf16x8*)(sVT + (nt * 16 + c) * 72 + kk * 32 + quad * 8);
                o[nt] = mfma16(a, bb, o[nt]);
            }
        }
        // ctx_h -> sQ (own rows; P consumed)
        #pragma unroll
        for (int nt = 0; nt < 8; ++nt)
            #pragma unroll
            for (int rr = 0; rr < 4; ++rr)
                sQ[(w * 16 + quad * 4 + rr) * 136 + nt * 16 + c] = f2bs(o[nt][rr]);
        // ---- out-proj partial: x += ctx_h @ Wo[:, h*128:+128]^T ----
        #pragma unroll
        for (int kk = 0; kk < 4; ++kk) {
            bf16x8 a = *(const bf16x8*)(sQ + (w * 16 + c) * 136 + kk * 32 + quad * 8);
            #pragma unroll
            for (int nt = 0; nt < 32; ++nt) {
                bf16x8 bb = *(const bf16x8*)(Wo + (size_t)(nt * 16 + c) * kD + h * 128 + kk * 32 + quad * 8);
                xacc[nt] = mfma16(a, bb, xacc[nt]);
            }
        }
    }

    // ---- epilogue: x = z_dc + att_out + bo; LayerNorm; store ----
    float sum[4] = {0, 0, 0, 0}, ssq[4] = {0, 0, 0, 0};
    #pragma unroll
    for (int nt = 0; nt < 32; ++nt)
        #pragma unroll
        for (int rr = 0; rr < 4; ++rr) {
            int trow = w * 16 + quad * 4 + rr;
            int col = nt * 16 + c;
            float zd = bs2f(zs[(size_t)trow * kD + col]) - 0.05f * (bs2f(sMean[col]) - bs2f(sZi[col]));
            float x = xacc[nt][rr] + bs2f(bo[col]) + zd;
            xacc[nt][rr] = x;
            sum[rr] += x; ssq[rr] += x * x;
        }
    float mu[4], rstd[4];
    #pragma unroll
    for (int rr = 0; rr < 4; ++rr) {
        float s = sum[rr], q = ssq[rr];
        for (int m = 1; m < 16; m <<= 1) { s += __shfl_xor(s, m, 64); q += __shfl_xor(q, m, 64); }
        float mm = s / (float)kD;
        float var = q / (float)kD - mm * mm;   // biased, eps 1e-5
        mu[rr] = mm;
        rstd[rr] = rsqrtf(var + 1e-5f);
    }
    #pragma unroll
    for (int nt = 0; nt < 32; ++nt)
        #pragma unroll
        for (int rr = 0; rr < 4; ++rr) {
            int trow = w * 16 + quad * 4 + rr;
            int col = nt * 16 + c;
            float v = (xacc[nt][rr] - mu[rr]) * rstd[rr] * bs2f(gm[col]) + bs2f(bt[col]);
            v = (v != v) ? 0.f : v;
            size_t idx = ((size_t)b * kT + trow) * kD + col;
            if (f32out) ((float*)outp)[idx] = v;
            else        ((s16*)outp)[idx] = f2bs(v);
        }
}

extern "C" void kernel_launch(void* const* d_in, const int* in_sizes, int n_in,
                              void* d_out, int out_size, void* d_ws, size_t ws_size,
                              hipStream_t stream) {
    (void)in_sizes; (void)n_in; (void)out_size;
    const size_t kStageElems = (size_t)kB * kT * kD;
    const size_t kNeed = 16 + (size_t)kTotalConv * 2 + kStageElems * 2;   // ~70.9 MB

    const s16* p[NSEG];
    s16* stage;
    void* outp = d_out;
    const int* flag = nullptr;
    int mode = 0;

    if (ws_size >= kNeed) {
        int* flg = (int*)d_ws;
        s16* conv = (s16*)((char*)d_ws + 16);
        stage = (s16*)((char*)d_ws + 16 + (size_t)kTotalConv * 2);
        detect_kernel<<<dim3(1), dim3(64), 0, stream>>>((const unsigned*)d_in[1], flg);
        ConvArgs ca;
        for (int i = 0; i < NSEG; ++i) ca.src[i] = d_in[i];
        convert_kernel<<<dim3(512), dim3(256), 0, stream>>>(ca, conv, flg);
        for (int i = 0; i < NSEG; ++i) p[i] = conv + kOff[i];
        flag = flg;
        mode = 1;
    } else {
        for (int i = 0; i < NSEG; ++i) p[i] = (const s16*)d_in[i];
        stage = (s16*)d_out;   // in-place staging (bf16 assumed)
    }

    ode_kernel<<<dim3(64), dim3(512), 0, stream>>>(
        p[0], p[1], p[2], p[3], p[4], p[5], p[6], p[7], stage);
    attn_kernel<<<dim3(kB), dim3(256), 0, stream>>>(
        p[0], p[8], p[9], p[10], p[11], p[12], p[13], stage, outp, flag, mode);
}